// Round 17
// baseline (60.916 us; speedup 1.0000x reference)
//
#include <hip/hip_runtime.h>
#include <hip/hip_bf16.h>
#include <cstdint>

typedef short  s16x8 __attribute__((ext_vector_type(8)));
typedef ushort u16x8 __attribute__((ext_vector_type(8)));
typedef ushort u16x4 __attribute__((ext_vector_type(4)));
typedef float  f32x4 __attribute__((ext_vector_type(4)));

#define B_    4
#define S_    1024
#define H_    12
#define D_    64
#define DIM_  768
// (1/sqrt(64)) * log2(e)
#define QSCALE 0.18033688011112042f
#define LOG2E  1.4426950408889634f

#define NGEMM 576   // 36 n-tiles (64-wide) x 16 m-tiles (128-tall)

__device__ __forceinline__ ushort f2bf(float f) {
    __bf16 h = (__bf16)f;          // RNE v_cvt on gfx950
    return __builtin_bit_cast(ushort, h);
}

__device__ __forceinline__ u16x8 cvt8(f32x4 x, f32x4 y) {
    u16x8 r;
    r[0]=f2bf(x[0]); r[1]=f2bf(x[1]); r[2]=f2bf(x[2]); r[3]=f2bf(x[3]);
    r[4]=f2bf(y[0]); r[5]=f2bf(y[1]); r[6]=f2bf(y[2]); r[7]=f2bf(y[3]);
    return r;
}

// ---------------------------------------------------------------------------
// K1 "qkv_gemm": R14's gemm part exactly (128x64 tile, BK=32, f32->bf16 cvt
// fused in staging, XCD-chunked swizzle), tail branch removed (now in attn).
// ---------------------------------------------------------------------------
__global__ __launch_bounds__(256) void qkv_gemm(
    const float* __restrict__ hidden, const float* __restrict__ W,
    const float* __restrict__ bvec, const int* __restrict__ cu,
    ushort* __restrict__ Qu, ushort* __restrict__ Ku, ushort* __restrict__ Vt)
{
    const int t = threadIdx.x;

    // XCD-chunked bijective swizzle over the gemm range (576 = 8 x 72)
    const int bid = ((int)blockIdx.x % 8) * (NGEMM/8) + (int)blockIdx.x / 8;

    __shared__ ushort As[128][40];   // 10.2 KB
    __shared__ ushort Bs[64][40];    //  5.1 KB

    const int n0 = (bid % 36) * 64;
    const int m0 = (bid / 36) * 128;
    const int w  = t >> 6, l = t & 63, lg = l >> 4, lc = l & 15;

    const int srow = t >> 1, shalf = t & 1;
    const int brow = t >> 2, bq = t & 3;
    const float* aSrc = hidden + (size_t)(m0 + srow) * DIM_ + shalf * 16;
    const float* bSrc = W      + (size_t)(n0 + brow) * DIM_ + bq * 8;

    f32x4 acc[2][4];
    #pragma unroll
    for (int i = 0; i < 2; i++)
        #pragma unroll
        for (int j = 0; j < 4; j++) acc[i][j] = (f32x4)0.0f;

    for (int k0 = 0; k0 < DIM_; k0 += 32) {
        __syncthreads();
        {
            const f32x4* a4 = (const f32x4*)(aSrc + k0);
            f32x4 x0 = a4[0], x1 = a4[1], x2 = a4[2], x3 = a4[3];
            const f32x4* b4 = (const f32x4*)(bSrc + k0);
            f32x4 y0 = b4[0], y1 = b4[1];
            *(u16x8*)&As[srow][shalf*16]     = cvt8(x0, x1);
            *(u16x8*)&As[srow][shalf*16 + 8] = cvt8(x2, x3);
            *(u16x8*)&Bs[brow][bq*8]         = cvt8(y0, y1);
        }
        __syncthreads();
        s16x8 af[2], bfr[4];
        #pragma unroll
        for (int mi = 0; mi < 2; mi++)
            af[mi] = *(const s16x8*)&As[w*32 + mi*16 + lc][lg*8];
        #pragma unroll
        for (int ni = 0; ni < 4; ni++)
            bfr[ni] = *(const s16x8*)&Bs[ni*16 + lc][lg*8];
        #pragma unroll
        for (int mi = 0; mi < 2; mi++)
            #pragma unroll
            for (int ni = 0; ni < 4; ni++)
                acc[mi][ni] = __builtin_amdgcn_mfma_f32_16x16x32_bf16(
                                  af[mi], bfr[ni], acc[mi][ni], 0, 0, 0);
    }

    const int sec = n0 / DIM_;   // 0=Q, 1=K, 2=V
    float bv[4];
    #pragma unroll
    for (int ni = 0; ni < 4; ni++) bv[ni] = bvec[n0 + ni*16 + lc];

    #pragma unroll
    for (int mi = 0; mi < 2; mi++) {
        const int r = m0 + w*32 + mi*16 + lg*4;
        if (sec == 2) {
            // V transposed; 4 consecutive tokens never straddle a batch
            // (cu entries are 512-multiples; span is 4-aligned).
            int b = 0;
            while (cu[b+1] <= r) b++;
            const int q = r - cu[b];
            #pragma unroll
            for (int ni = 0; ni < 4; ni++) {
                const int nl = (n0 - 2*DIM_) + ni*16 + lc;
                const int h = nl >> 6, d = nl & 63;
                u16x4 pk;
                #pragma unroll
                for (int j = 0; j < 4; j++) pk[j] = f2bf(acc[mi][ni][j] + bv[ni]);
                *(u16x4*)&Vt[((size_t)((b*H_ + h)*64 + d))*S_ + q] = pk;
            }
        } else {
            #pragma unroll
            for (int j = 0; j < 4; j++) {
                #pragma unroll
                for (int ni = 0; ni < 4; ni++) {
                    const int nl = (n0 - sec*DIM_) + ni*16 + lc;
                    float v = acc[mi][ni][j] + bv[ni];
                    if (sec == 0) Qu[(size_t)(r+j)*DIM_ + nl] = f2bf(v * QSCALE);
                    else          Ku[(size_t)(r+j)*DIM_ + nl] = f2bf(v);
                }
            }
        }
    }
}

// ---------------------------------------------------------------------------
// K2: flash attention (R14's QBLK=32, 2 waves/block) + IN-BLOCK bias tail:
// each block computes tailS[row] = sum_{k>=Lb} 2^(bias*log2e) for its own 32
// q-rows during the prologue (overlaps tile-0 prefetch latency), replacing
// the global T buffer and its cross-kernel dependency.
// ---------------------------------------------------------------------------
__global__ __launch_bounds__(128) void attn_kernel(
    const ushort* __restrict__ Qu, const ushort* __restrict__ Ku,
    const ushort* __restrict__ Vt, const float* __restrict__ bias,
    const int* __restrict__ cu, float* __restrict__ out)
{
    const int b  = blockIdx.x >> 4, qt = blockIdx.x & 15;   // 16 q-tiles of 32
    const int h  = blockIdx.y;
    const int cu0 = cu[b];
    const int Lb  = cu[b+1] - cu0;
    const int qbase = qt * 32;
    if (qbase >= Lb) return;

    const int t = threadIdx.x, w = t >> 6, l = t & 63, lg = l >> 4, lc = l & 15;

    __shared__ ushort Ks[64][72];     // 9.2 KB
    __shared__ ushort Vs[80][72];     // 11.5 KB  Vs[d][k]; rows 64..79 ones-block
    __shared__ ushort Ps[2][16][72];  // 4.6 KB   per-wave P staging
    __shared__ float  tailS[32];      // per-row bias-only tail sums

    // ones-block rows 64..79 (row 64 = 1.0, rest 0)
    for (int i = t; i < 16*9; i += 128) {
        const int row = 64 + i/9, ch = i%9;
        u16x8 v = (u16x8)0;
        if (row == 64 && ch < 8)
            #pragma unroll
            for (int e = 0; e < 8; e++) v[e] = 0x3F80;  // bf16 1.0
        *(u16x8*)&Vs[row][ch*8] = v;
    }

    const float*  bias_b = bias + (size_t)(b*H_ + h)*S_*S_;
    const ushort* kbase  = Ku + (size_t)cu0*DIM_ + h*64;
    const ushort* vbase  = Vt + (size_t)((b*H_ + h)*64)*S_;

    const int krow = t >> 3, kch = t & 7;   // staging: rows krow+i*16, i=0..3

    // C-fragment q rows: rl + j (block-local), j=0..3
    const int rl = w*16 + lg*4;
    int p_[4]; bool val_[4];
    const float* bpr[4];
    #pragma unroll
    for (int j = 0; j < 4; j++) {
        const int r = qbase + rl + j;
        val_[j] = (r < Lb);
        p_[j]   = val_[j] ? r : (Lb - 1);
        bpr[j]  = bias_b + (size_t)p_[j]*S_;
    }

    // Q A-fragments (row = lc), pre-scaled in GEMM epilogue
    int qar = qbase + w*16 + lc; if (qar >= Lb) qar = Lb - 1;
    const ushort* qp = Qu + (size_t)(cu0 + qar)*DIM_ + h*64;
    s16x8 qa0 = *(const s16x8*)(qp + lg*8);
    s16x8 qa1 = *(const s16x8*)(qp + 32 + lg*8);

    f32x4 O[4], lsum;
    #pragma unroll
    for (int d = 0; d < 4; d++) O[d] = (f32x4)0.0f;
    lsum = (f32x4)0.0f;

    // prologue: prefetch tile 0 (bias -> regs, K/V -> regs)
    float pf[4][4];
    u16x8 kr[4], vr[4];
    #pragma unroll
    for (int f = 0; f < 4; f++)
        #pragma unroll
        for (int j = 0; j < 4; j++) pf[f][j] = bpr[j][f*16 + lc];
    #pragma unroll
    for (int i = 0; i < 4; i++) {
        const int r  = krow + i*16;
        const int rc = (r < Lb) ? r : Lb - 1;
        kr[i] = *(const u16x8*)(kbase + (size_t)rc*DIM_ + kch*8);
        vr[i] = *(const u16x8*)(vbase + (size_t)r*S_ + kch*8);
    }

    // in-block bias tail: rows qbase..qbase+31, cols [Lb, S).
    // 4 lanes per row (tc4 = t&3); batched 8-deep for load ILP.
    {
        const int trow = t >> 2, tc4 = t & 3;
        int trq = qbase + trow; if (trq >= Lb) trq = Lb - 1;
        const float* rp = bias_b + (size_t)trq*S_;
        float ts = 0.0f;
        for (int kb = Lb; kb < S_; kb += 128) {
            f32x4 v[8];
            #pragma unroll
            for (int i = 0; i < 8; i++) {
                const int k = kb + tc4*4 + i*16;
                v[i] = (k < S_) ? *(const f32x4*)(rp + k) : (f32x4)(-1e30f);
            }
            #pragma unroll
            for (int i = 0; i < 8; i++)
                ts += exp2f(v[i][0]*LOG2E) + exp2f(v[i][1]*LOG2E)
                    + exp2f(v[i][2]*LOG2E) + exp2f(v[i][3]*LOG2E);
        }
        ts += __shfl_xor(ts, 1, 64);
        ts += __shfl_xor(ts, 2, 64);
        if (tc4 == 0) tailS[trow] = ts;
        // visibility: first __syncthreads in the k-loop below
    }

    for (int k0 = 0; k0 < Lb; k0 += 64) {
        __syncthreads();                 // previous tile's LDS reads done
        #pragma unroll
        for (int i = 0; i < 4; i++) {
            const int r = krow + i*16;
            u16x8 kz = (k0 + r < Lb) ? kr[i] : (u16x8)0;
            *(u16x8*)&Ks[r][kch*8] = kz;
            *(u16x8*)&Vs[r][kch*8] = vr[i];
        }
        __syncthreads();

        // consume prefetched bias into score C-frags (pre-mul log2e)
        f32x4 sc[4];
        #pragma unroll
        for (int f = 0; f < 4; f++)
            #pragma unroll
            for (int j = 0; j < 4; j++) sc[f][j] = pf[f][j] * LOG2E;

        // prefetch next tile (in flight during compute below)
        const int kn = k0 + 64;
        if (kn < Lb) {
            #pragma unroll
            for (int f = 0; f < 4; f++)
                #pragma unroll
                for (int j = 0; j < 4; j++) pf[f][j] = bpr[j][kn + f*16 + lc];
            #pragma unroll
            for (int i = 0; i < 4; i++) {
                const int r  = krow + i*16;
                const int rc = (kn + r < Lb) ? kn + r : Lb - 1;
                kr[i] = *(const u16x8*)(kbase + (size_t)rc*DIM_ + kch*8);
                vr[i] = *(const u16x8*)(vbase + (size_t)r*S_ + kn + kch*8);
            }
        }

        // QK^T
        #pragma unroll
        for (int f = 0; f < 4; f++) {
            s16x8 kb0 = *(const s16x8*)&Ks[f*16 + lc][lg*8];
            s16x8 kb1 = *(const s16x8*)&Ks[f*16 + lc][32 + lg*8];
            sc[f] = __builtin_amdgcn_mfma_f32_16x16x32_bf16(qa0, kb0, sc[f], 0,0,0);
            sc[f] = __builtin_amdgcn_mfma_f32_16x16x32_bf16(qa1, kb1, sc[f], 0,0,0);
        }
        // mask last-tile columns beyond Lb (tail pass owns them)
        if (k0 + 64 > Lb) {
            #pragma unroll
            for (int f = 0; f < 4; f++) {
                const int kcol = k0 + f*16 + lc;
                if (kcol >= Lb)
                    #pragma unroll
                    for (int j = 0; j < 4; j++) sc[f][j] = -1e30f;
            }
        }

        // P = 2^sc directly (no max tracking; bounded scores)
        #pragma unroll
        for (int f = 0; f < 4; f++)
            #pragma unroll
            for (int j = 0; j < 4; j++)
                Ps[w][lg*4 + j][f*16 + lc] = f2bf(exp2f(sc[f][j]));

        s16x8 pa0 = *(const s16x8*)&Ps[w][lc][lg*8];
        s16x8 pa1 = *(const s16x8*)&Ps[w][lc][32 + lg*8];
        #pragma unroll
        for (int df = 0; df < 4; df++) {
            s16x8 vb0 = *(const s16x8*)&Vs[df*16 + lc][lg*8];
            s16x8 vb1 = *(const s16x8*)&Vs[df*16 + lc][32 + lg*8];
            O[df] = __builtin_amdgcn_mfma_f32_16x16x32_bf16(pa0, vb0, O[df], 0,0,0);
            O[df] = __builtin_amdgcn_mfma_f32_16x16x32_bf16(pa1, vb1, O[df], 0,0,0);
        }
        // rowsum via ones-block (col lc==0 of result = sum_k P)
        {
            s16x8 ob0 = *(const s16x8*)&Vs[64 + lc][lg*8];
            s16x8 ob1 = *(const s16x8*)&Vs[64 + lc][32 + lg*8];
            lsum = __builtin_amdgcn_mfma_f32_16x16x32_bf16(pa0, ob0, lsum, 0,0,0);
            lsum = __builtin_amdgcn_mfma_f32_16x16x32_bf16(pa1, ob1, lsum, 0,0,0);
        }
    }

    // denominator: rowsum (valid k) + in-block bias tail; broadcast from lc==0
    #pragma unroll
    for (int j = 0; j < 4; j++) {
        float lj = lsum[j] + tailS[rl + j];
        float inv = 1.0f / lj;
        inv = __shfl(inv, l & 48, 64);       // lane with lc==0 in this group
        if (val_[j]) {
            float* op = out + (size_t)(cu0 + qbase + rl + j)*DIM_ + h*64;
            #pragma unroll
            for (int df = 0; df < 4; df++) op[df*16 + lc] = O[df][j] * inv;
        }
    }
}

// ---------------------------------------------------------------------------
extern "C" void kernel_launch(void* const* d_in, const int* in_sizes, int n_in,
                              void* d_out, int out_size, void* d_ws, size_t ws_size,
                              hipStream_t stream)
{
    const float* hidden  = (const float*)d_in[0];
    const float* W       = (const float*)d_in[1];
    const float* bvec    = (const float*)d_in[2];
    const float* bias    = (const float*)d_in[3];
    const int*   cu      = (const int*)d_in[6];
    float*       out     = (float*)d_out;

    const int NNZ = in_sizes[0] / DIM_;            // 2048

    char* ws = (char*)d_ws;
    const size_t uB = (size_t)NNZ * DIM_ * 2;      // one unpadded qkv section
    ushort* Qu = (ushort*)(ws);
    ushort* Ku = (ushort*)(ws + uB);
    ushort* Vt = (ushort*)(ws + 2*uB);

    qkv_gemm<<<NGEMM, 256, 0, stream>>>(hidden, W, bvec, cu, Qu, Ku, Vt);

    dim3 ga(B_*16, H_);                            // (64,12), QBLK=32
    attn_kernel<<<ga, 128, 0, stream>>>(Qu, Ku, Vt, bias, cu, out);
}

// Round 18
// 57.368 us; speedup vs baseline: 1.0618x; 1.0618x over previous
//
#include <hip/hip_runtime.h>
#include <hip/hip_bf16.h>
#include <cstdint>

typedef short  s16x8 __attribute__((ext_vector_type(8)));
typedef ushort u16x8 __attribute__((ext_vector_type(8)));
typedef ushort u16x4 __attribute__((ext_vector_type(4)));
typedef float  f32x4 __attribute__((ext_vector_type(4)));

#define B_    4
#define S_    1024
#define H_    12
#define D_    64
#define DIM_  768
// (1/sqrt(64)) * log2(e)
#define QSCALE 0.18033688011112042f
#define LOG2E  1.4426950408889634f

#define NTAIL 384   // tail-reduce blocks appended to the gemm grid
#define NGEMM 576   // 36 n-tiles (64-wide) x 16 m-tiles (128-tall)

__device__ __forceinline__ ushort f2bf(float f) {
    __bf16 h = (__bf16)f;          // RNE v_cvt on gfx950
    return __builtin_bit_cast(ushort, h);
}

__device__ __forceinline__ u16x8 cvt8(f32x4 x, f32x4 y) {
    u16x8 r;
    r[0]=f2bf(x[0]); r[1]=f2bf(x[1]); r[2]=f2bf(x[2]); r[3]=f2bf(x[3]);
    r[4]=f2bf(y[0]); r[5]=f2bf(y[1]); r[6]=f2bf(y[2]); r[7]=f2bf(y[3]);
    return r;
}

// ---------------------------------------------------------------------------
// K1 "gemm_tail": blocks [0,NGEMM): 128x64-tile GEMM (f32->bf16 cvt fused in
//   LDS staging, BK=32, XCD-chunked swizzle). Q pre-scaled; V transposed to
//   Vt[(b*H+h)*64+d][q_local].
// blocks [NGEMM,+NTAIL): tail-T = sum_{k>=Lb} 2^(bias*log2e), batched-ILP
//   loads (8 in flight); overlaps the gemm blocks in the same dispatch.
// ---------------------------------------------------------------------------
__global__ __launch_bounds__(256) void gemm_tail(
    const float* __restrict__ hidden, const float* __restrict__ W,
    const float* __restrict__ bvec, const float* __restrict__ bias,
    const int* __restrict__ cu,
    ushort* __restrict__ Qu, ushort* __restrict__ Ku, ushort* __restrict__ Vt,
    float* __restrict__ T, int nrows, int nnz)
{
    const int t = threadIdx.x;

    if ((int)blockIdx.x >= NGEMM) {
        const int blk = blockIdx.x - NGEMM;
        const int w = t >> 6, l = t & 63, grp = l >> 4, lc = l & 15;
        for (int rid = blk*16 + w*4 + grp; rid < nrows; rid += NTAIL*16) {
            const int h = rid / nnz;
            const int u = rid - h * nnz;
            int b = 0;
            while (cu[b+1] <= u) b++;
            const int q  = u - cu[b];
            const int Lb = cu[b+1] - cu[b];
            const float* rp = bias + ((size_t)(b*H_ + h)*S_ + q)*S_;
            float s = 0.0f;
            for (int kbase = Lb; kbase < S_; kbase += 512) {
                f32x4 v[8];
                #pragma unroll
                for (int i = 0; i < 8; i++) {          // batch-issue: 8 in flight
                    const int k = kbase + lc*4 + i*64;
                    v[i] = (k < S_) ? *(const f32x4*)(rp + k) : (f32x4)(-1e30f);
                }
                #pragma unroll
                for (int i = 0; i < 8; i++)
                    s += exp2f(v[i][0]*LOG2E) + exp2f(v[i][1]*LOG2E)
                       + exp2f(v[i][2]*LOG2E) + exp2f(v[i][3]*LOG2E);
            }
            s += __shfl_xor(s, 1, 64);
            s += __shfl_xor(s, 2, 64);
            s += __shfl_xor(s, 4, 64);
            s += __shfl_xor(s, 8, 64);
            if (lc == 0) T[(size_t)(b*H_ + h)*S_ + q] = s;
        }
        return;
    }

    // XCD-chunked bijective swizzle over the gemm range (576 = 8 x 72)
    const int bid = ((int)blockIdx.x % 8) * (NGEMM/8) + (int)blockIdx.x / 8;

    __shared__ ushort As[128][40];   // 10.2 KB
    __shared__ ushort Bs[64][40];    //  5.1 KB

    const int n0 = (bid % 36) * 64;
    const int m0 = (bid / 36) * 128;
    const int w  = t >> 6, l = t & 63, lg = l >> 4, lc = l & 15;

    const int srow = t >> 1, shalf = t & 1;
    const int brow = t >> 2, bq = t & 3;
    const float* aSrc = hidden + (size_t)(m0 + srow) * DIM_ + shalf * 16;
    const float* bSrc = W      + (size_t)(n0 + brow) * DIM_ + bq * 8;

    f32x4 acc[2][4];
    #pragma unroll
    for (int i = 0; i < 2; i++)
        #pragma unroll
        for (int j = 0; j < 4; j++) acc[i][j] = (f32x4)0.0f;

    for (int k0 = 0; k0 < DIM_; k0 += 32) {
        __syncthreads();
        {
            const f32x4* a4 = (const f32x4*)(aSrc + k0);
            f32x4 x0 = a4[0], x1 = a4[1], x2 = a4[2], x3 = a4[3];
            const f32x4* b4 = (const f32x4*)(bSrc + k0);
            f32x4 y0 = b4[0], y1 = b4[1];
            *(u16x8*)&As[srow][shalf*16]     = cvt8(x0, x1);
            *(u16x8*)&As[srow][shalf*16 + 8] = cvt8(x2, x3);
            *(u16x8*)&Bs[brow][bq*8]         = cvt8(y0, y1);
        }
        __syncthreads();
        s16x8 af[2], bfr[4];
        #pragma unroll
        for (int mi = 0; mi < 2; mi++)
            af[mi] = *(const s16x8*)&As[w*32 + mi*16 + lc][lg*8];
        #pragma unroll
        for (int ni = 0; ni < 4; ni++)
            bfr[ni] = *(const s16x8*)&Bs[ni*16 + lc][lg*8];
        #pragma unroll
        for (int mi = 0; mi < 2; mi++)
            #pragma unroll
            for (int ni = 0; ni < 4; ni++)
                acc[mi][ni] = __builtin_amdgcn_mfma_f32_16x16x32_bf16(
                                  af[mi], bfr[ni], acc[mi][ni], 0, 0, 0);
    }

    const int sec = n0 / DIM_;   // 0=Q, 1=K, 2=V
    float bv[4];
    #pragma unroll
    for (int ni = 0; ni < 4; ni++) bv[ni] = bvec[n0 + ni*16 + lc];

    #pragma unroll
    for (int mi = 0; mi < 2; mi++) {
        const int r = m0 + w*32 + mi*16 + lg*4;
        if (sec == 2) {
            // V transposed; 4 consecutive tokens never straddle a batch
            // (cu entries are 512-multiples; span is 4-aligned).
            int b = 0;
            while (cu[b+1] <= r) b++;
            const int q = r - cu[b];
            #pragma unroll
            for (int ni = 0; ni < 4; ni++) {
                const int nl = (n0 - 2*DIM_) + ni*16 + lc;
                const int h = nl >> 6, d = nl & 63;
                u16x4 pk;
                #pragma unroll
                for (int j = 0; j < 4; j++) pk[j] = f2bf(acc[mi][ni][j] + bv[ni]);
                *(u16x4*)&Vt[((size_t)((b*H_ + h)*64 + d))*S_ + q] = pk;
            }
        } else {
            #pragma unroll
            for (int j = 0; j < 4; j++) {
                #pragma unroll
                for (int ni = 0; ni < 4; ni++) {
                    const int nl = (n0 - sec*DIM_) + ni*16 + lc;
                    float v = acc[mi][ni][j] + bv[ni];
                    if (sec == 0) Qu[(size_t)(r+j)*DIM_ + nl] = f2bf(v * QSCALE);
                    else          Ku[(size_t)(r+j)*DIM_ + nl] = f2bf(v);
                }
            }
        }
    }
}

// ---------------------------------------------------------------------------
// K2: flash attention, QBLK=32, 2 waves/block (128 thr), 768 all-live blocks.
// No max tracking (bounded scores); rowsum via ones-row MFMA; bias-only tail
// merged from T.
// ---------------------------------------------------------------------------
__global__ __launch_bounds__(128) void attn_kernel(
    const ushort* __restrict__ Qu, const ushort* __restrict__ Ku,
    const ushort* __restrict__ Vt, const float* __restrict__ bias,
    const float* __restrict__ T, const int* __restrict__ cu,
    float* __restrict__ out)
{
    const int b  = blockIdx.x >> 4, qt = blockIdx.x & 15;   // 16 q-tiles of 32
    const int h  = blockIdx.y;
    const int cu0 = cu[b];
    const int Lb  = cu[b+1] - cu0;
    const int qbase = qt * 32;
    if (qbase >= Lb) return;

    const int t = threadIdx.x, w = t >> 6, l = t & 63, lg = l >> 4, lc = l & 15;

    __shared__ ushort Ks[64][72];     // 9.2 KB
    __shared__ ushort Vs[80][72];     // 11.5 KB  Vs[d][k]; rows 64..79 ones-block
    __shared__ ushort Ps[2][16][72];  // 4.6 KB   per-wave P staging

    // ones-block rows 64..79 (row 64 = 1.0, rest 0)
    for (int i = t; i < 16*9; i += 128) {
        const int row = 64 + i/9, ch = i%9;
        u16x8 v = (u16x8)0;
        if (row == 64 && ch < 8)
            #pragma unroll
            for (int e = 0; e < 8; e++) v[e] = 0x3F80;  // bf16 1.0
        *(u16x8*)&Vs[row][ch*8] = v;
    }

    const float*  bias_b = bias + (size_t)(b*H_ + h)*S_*S_;
    const ushort* kbase  = Ku + (size_t)cu0*DIM_ + h*64;
    const ushort* vbase  = Vt + (size_t)((b*H_ + h)*64)*S_;

    const int krow = t >> 3, kch = t & 7;   // staging: rows krow+i*16, i=0..3

    // C-fragment q rows: rl + j (block-local), j=0..3
    const int rl = w*16 + lg*4;
    int p_[4]; bool val_[4];
    const float* bpr[4];
    #pragma unroll
    for (int j = 0; j < 4; j++) {
        const int r = qbase + rl + j;
        val_[j] = (r < Lb);
        p_[j]   = val_[j] ? r : (Lb - 1);
        bpr[j]  = bias_b + (size_t)p_[j]*S_;
    }

    // Q A-fragments (row = lc), pre-scaled in GEMM epilogue
    int qar = qbase + w*16 + lc; if (qar >= Lb) qar = Lb - 1;
    const ushort* qp = Qu + (size_t)(cu0 + qar)*DIM_ + h*64;
    s16x8 qa0 = *(const s16x8*)(qp + lg*8);
    s16x8 qa1 = *(const s16x8*)(qp + 32 + lg*8);

    f32x4 O[4], lsum;
    #pragma unroll
    for (int d = 0; d < 4; d++) O[d] = (f32x4)0.0f;
    lsum = (f32x4)0.0f;

    // prologue: prefetch tile 0 (bias -> regs, K/V -> regs)
    float pf[4][4];
    u16x8 kr[4], vr[4];
    #pragma unroll
    for (int f = 0; f < 4; f++)
        #pragma unroll
        for (int j = 0; j < 4; j++) pf[f][j] = bpr[j][f*16 + lc];
    #pragma unroll
    for (int i = 0; i < 4; i++) {
        const int r  = krow + i*16;
        const int rc = (r < Lb) ? r : Lb - 1;
        kr[i] = *(const u16x8*)(kbase + (size_t)rc*DIM_ + kch*8);
        vr[i] = *(const u16x8*)(vbase + (size_t)r*S_ + kch*8);
    }

    for (int k0 = 0; k0 < Lb; k0 += 64) {
        __syncthreads();                 // previous tile's LDS reads done
        #pragma unroll
        for (int i = 0; i < 4; i++) {
            const int r = krow + i*16;
            u16x8 kz = (k0 + r < Lb) ? kr[i] : (u16x8)0;
            *(u16x8*)&Ks[r][kch*8] = kz;
            *(u16x8*)&Vs[r][kch*8] = vr[i];
        }
        __syncthreads();

        // consume prefetched bias into score C-frags (pre-mul log2e)
        f32x4 sc[4];
        #pragma unroll
        for (int f = 0; f < 4; f++)
            #pragma unroll
            for (int j = 0; j < 4; j++) sc[f][j] = pf[f][j] * LOG2E;

        // prefetch next tile (in flight during compute below)
        const int kn = k0 + 64;
        if (kn < Lb) {
            #pragma unroll
            for (int f = 0; f < 4; f++)
                #pragma unroll
                for (int j = 0; j < 4; j++) pf[f][j] = bpr[j][kn + f*16 + lc];
            #pragma unroll
            for (int i = 0; i < 4; i++) {
                const int r  = krow + i*16;
                const int rc = (kn + r < Lb) ? kn + r : Lb - 1;
                kr[i] = *(const u16x8*)(kbase + (size_t)rc*DIM_ + kch*8);
                vr[i] = *(const u16x8*)(vbase + (size_t)r*S_ + kn + kch*8);
            }
        }

        // QK^T
        #pragma unroll
        for (int f = 0; f < 4; f++) {
            s16x8 kb0 = *(const s16x8*)&Ks[f*16 + lc][lg*8];
            s16x8 kb1 = *(const s16x8*)&Ks[f*16 + lc][32 + lg*8];
            sc[f] = __builtin_amdgcn_mfma_f32_16x16x32_bf16(qa0, kb0, sc[f], 0,0,0);
            sc[f] = __builtin_amdgcn_mfma_f32_16x16x32_bf16(qa1, kb1, sc[f], 0,0,0);
        }
        // mask last-tile columns beyond Lb (tail kernel owns them)
        if (k0 + 64 > Lb) {
            #pragma unroll
            for (int f = 0; f < 4; f++) {
                const int kcol = k0 + f*16 + lc;
                if (kcol >= Lb)
                    #pragma unroll
                    for (int j = 0; j < 4; j++) sc[f][j] = -1e30f;
            }
        }

        // P = 2^sc directly (no max tracking; bounded scores)
        #pragma unroll
        for (int f = 0; f < 4; f++)
            #pragma unroll
            for (int j = 0; j < 4; j++)
                Ps[w][lg*4 + j][f*16 + lc] = f2bf(exp2f(sc[f][j]));

        s16x8 pa0 = *(const s16x8*)&Ps[w][lc][lg*8];
        s16x8 pa1 = *(const s16x8*)&Ps[w][lc][32 + lg*8];
        #pragma unroll
        for (int df = 0; df < 4; df++) {
            s16x8 vb0 = *(const s16x8*)&Vs[df*16 + lc][lg*8];
            s16x8 vb1 = *(const s16x8*)&Vs[df*16 + lc][32 + lg*8];
            O[df] = __builtin_amdgcn_mfma_f32_16x16x32_bf16(pa0, vb0, O[df], 0,0,0);
            O[df] = __builtin_amdgcn_mfma_f32_16x16x32_bf16(pa1, vb1, O[df], 0,0,0);
        }
        // rowsum via ones-block (col lc==0 of result = sum_k P)
        {
            s16x8 ob0 = *(const s16x8*)&Vs[64 + lc][lg*8];
            s16x8 ob1 = *(const s16x8*)&Vs[64 + lc][32 + lg*8];
            lsum = __builtin_amdgcn_mfma_f32_16x16x32_bf16(pa0, ob0, lsum, 0,0,0);
            lsum = __builtin_amdgcn_mfma_f32_16x16x32_bf16(pa1, ob1, lsum, 0,0,0);
        }
    }

    // denominator: rowsum (valid k) + bias-only tail T; broadcast from lc==0
    #pragma unroll
    for (int j = 0; j < 4; j++) {
        float lj = lsum[j] + T[(size_t)(b*H_ + h)*S_ + p_[j]];
        float inv = 1.0f / lj;
        inv = __shfl(inv, l & 48, 64);       // lane with lc==0 in this group
        if (val_[j]) {
            float* op = out + (size_t)(cu0 + qbase + rl + j)*DIM_ + h*64;
            #pragma unroll
            for (int df = 0; df < 4; df++) op[df*16 + lc] = O[df][j] * inv;
        }
    }
}

// ---------------------------------------------------------------------------
extern "C" void kernel_launch(void* const* d_in, const int* in_sizes, int n_in,
                              void* d_out, int out_size, void* d_ws, size_t ws_size,
                              hipStream_t stream)
{
    const float* hidden  = (const float*)d_in[0];
    const float* W       = (const float*)d_in[1];
    const float* bvec    = (const float*)d_in[2];
    const float* bias    = (const float*)d_in[3];
    const int*   cu      = (const int*)d_in[6];
    float*       out     = (float*)d_out;

    const int NNZ   = in_sizes[0] / DIM_;          // 2048
    const int nrows = NNZ * H_;                    // 24576 tail rows

    char* ws = (char*)d_ws;
    const size_t uB  = (size_t)NNZ * DIM_ * 2;     // one unpadded qkv section
    const size_t vtB = (size_t)B_ * H_ * 64 * S_ * 2;
    ushort* Qu = (ushort*)(ws);
    ushort* Ku = (ushort*)(ws + uB);
    ushort* Vt = (ushort*)(ws + 2*uB);
    float*  T  = (float*)(ws + 2*uB + vtB);

    gemm_tail<<<NGEMM + NTAIL, 256, 0, stream>>>(hidden, W, bvec, bias, cu,
                                                 Qu, Ku, Vt, T, nrows, NNZ);

    dim3 ga(B_*16, H_);                            // (64,12), QBLK=32
    attn_kernel<<<ga, 128, 0, stream>>>(Qu, Ku, Vt, bias, T, cu, out);
}

// Round 19
// 57.305 us; speedup vs baseline: 1.0630x; 1.0011x over previous
//
#include <hip/hip_runtime.h>
#include <hip/hip_bf16.h>
#include <cstdint>

typedef short  s16x8 __attribute__((ext_vector_type(8)));
typedef ushort u16x8 __attribute__((ext_vector_type(8)));
typedef ushort u16x4 __attribute__((ext_vector_type(4)));
typedef float  f32x4 __attribute__((ext_vector_type(4)));

#define B_    4
#define S_    1024
#define H_    12
#define D_    64
#define DIM_  768
// (1/sqrt(64)) * log2(e)
#define QSCALE 0.18033688011112042f
#define LOG2E  1.4426950408889634f

#define NTAIL 384   // tail-reduce blocks appended to the gemm grid
#define NGEMM 576   // 36 n-tiles (64-wide) x 16 m-tiles (128-tall)

__device__ __forceinline__ ushort f2bf(float f) {
    __bf16 h = (__bf16)f;          // RNE v_cvt on gfx950
    return __builtin_bit_cast(ushort, h);
}

__device__ __forceinline__ u16x8 cvt8(f32x4 x, f32x4 y) {
    u16x8 r;
    r[0]=f2bf(x[0]); r[1]=f2bf(x[1]); r[2]=f2bf(x[2]); r[3]=f2bf(x[3]);
    r[4]=f2bf(y[0]); r[5]=f2bf(y[1]); r[6]=f2bf(y[2]); r[7]=f2bf(y[3]);
    return r;
}

// ---------------------------------------------------------------------------
// K1 "gemm_tail": blocks [0,NGEMM): 128x64-tile GEMM, BK=32, with REGISTER
//   PREFETCH: k-step n+1's 6 global loads (24 VGPR) issue right after step
//   n's staging barrier, hiding L3 latency under the MFMA phase. (R10's
//   version of this failed via 64-VGPR prefetch on a 64-VGPR-acc tile; here
//   it is 24 on a 32-acc tile -- no spill.) Math order identical to R18.
// blocks [NGEMM,+NTAIL): tail-T, batched-ILP loads (R14, unchanged).
// ---------------------------------------------------------------------------
__global__ __launch_bounds__(256) void gemm_tail(
    const float* __restrict__ hidden, const float* __restrict__ W,
    const float* __restrict__ bvec, const float* __restrict__ bias,
    const int* __restrict__ cu,
    ushort* __restrict__ Qu, ushort* __restrict__ Ku, ushort* __restrict__ Vt,
    float* __restrict__ T, int nrows, int nnz)
{
    const int t = threadIdx.x;

    if ((int)blockIdx.x >= NGEMM) {
        const int blk = blockIdx.x - NGEMM;
        const int w = t >> 6, l = t & 63, grp = l >> 4, lc = l & 15;
        for (int rid = blk*16 + w*4 + grp; rid < nrows; rid += NTAIL*16) {
            const int h = rid / nnz;
            const int u = rid - h * nnz;
            int b = 0;
            while (cu[b+1] <= u) b++;
            const int q  = u - cu[b];
            const int Lb = cu[b+1] - cu[b];
            const float* rp = bias + ((size_t)(b*H_ + h)*S_ + q)*S_;
            float s = 0.0f;
            for (int kbase = Lb; kbase < S_; kbase += 512) {
                f32x4 v[8];
                #pragma unroll
                for (int i = 0; i < 8; i++) {          // batch-issue: 8 in flight
                    const int k = kbase + lc*4 + i*64;
                    v[i] = (k < S_) ? *(const f32x4*)(rp + k) : (f32x4)(-1e30f);
                }
                #pragma unroll
                for (int i = 0; i < 8; i++)
                    s += exp2f(v[i][0]*LOG2E) + exp2f(v[i][1]*LOG2E)
                       + exp2f(v[i][2]*LOG2E) + exp2f(v[i][3]*LOG2E);
            }
            s += __shfl_xor(s, 1, 64);
            s += __shfl_xor(s, 2, 64);
            s += __shfl_xor(s, 4, 64);
            s += __shfl_xor(s, 8, 64);
            if (lc == 0) T[(size_t)(b*H_ + h)*S_ + q] = s;
        }
        return;
    }

    // XCD-chunked bijective swizzle over the gemm range (576 = 8 x 72)
    const int bid = ((int)blockIdx.x % 8) * (NGEMM/8) + (int)blockIdx.x / 8;

    __shared__ ushort As[128][40];   // 10.2 KB
    __shared__ ushort Bs[64][40];    //  5.1 KB

    const int n0 = (bid % 36) * 64;
    const int m0 = (bid / 36) * 128;
    const int w  = t >> 6, l = t & 63, lg = l >> 4, lc = l & 15;

    const int srow = t >> 1, shalf = t & 1;
    const int brow = t >> 2, bq = t & 3;
    const float* aSrc = hidden + (size_t)(m0 + srow) * DIM_ + shalf * 16;
    const float* bSrc = W      + (size_t)(n0 + brow) * DIM_ + bq * 8;

    f32x4 acc[2][4];
    #pragma unroll
    for (int i = 0; i < 2; i++)
        #pragma unroll
        for (int j = 0; j < 4; j++) acc[i][j] = (f32x4)0.0f;

    // prologue: prefetch k-step 0 into registers (4 f32x4 A + 2 f32x4 B)
    f32x4 pfA[4], pfB[2];
    #pragma unroll
    for (int i = 0; i < 4; i++) pfA[i] = *(const f32x4*)(aSrc + i*4);
    pfB[0] = *(const f32x4*)(bSrc);
    pfB[1] = *(const f32x4*)(bSrc + 4);

    for (int k0 = 0; k0 < DIM_; k0 += 32) {
        __syncthreads();                 // previous step's LDS reads done
        *(u16x8*)&As[srow][shalf*16]     = cvt8(pfA[0], pfA[1]);
        *(u16x8*)&As[srow][shalf*16 + 8] = cvt8(pfA[2], pfA[3]);
        *(u16x8*)&Bs[brow][bq*8]         = cvt8(pfB[0], pfB[1]);
        __syncthreads();                 // writes visible

        // issue NEXT step's loads now -- they land during the MFMA phase
        // below + the next barrier wait (clamped redundant load on last step)
        const int kn = (k0 + 32 < DIM_) ? k0 + 32 : k0;
        #pragma unroll
        for (int i = 0; i < 4; i++) pfA[i] = *(const f32x4*)(aSrc + kn + i*4);
        pfB[0] = *(const f32x4*)(bSrc + kn);
        pfB[1] = *(const f32x4*)(bSrc + kn + 4);

        s16x8 af[2], bfr[4];
        #pragma unroll
        for (int mi = 0; mi < 2; mi++)
            af[mi] = *(const s16x8*)&As[w*32 + mi*16 + lc][lg*8];
        #pragma unroll
        for (int ni = 0; ni < 4; ni++)
            bfr[ni] = *(const s16x8*)&Bs[ni*16 + lc][lg*8];
        #pragma unroll
        for (int mi = 0; mi < 2; mi++)
            #pragma unroll
            for (int ni = 0; ni < 4; ni++)
                acc[mi][ni] = __builtin_amdgcn_mfma_f32_16x16x32_bf16(
                                  af[mi], bfr[ni], acc[mi][ni], 0, 0, 0);
    }

    const int sec = n0 / DIM_;   // 0=Q, 1=K, 2=V
    float bv[4];
    #pragma unroll
    for (int ni = 0; ni < 4; ni++) bv[ni] = bvec[n0 + ni*16 + lc];

    #pragma unroll
    for (int mi = 0; mi < 2; mi++) {
        const int r = m0 + w*32 + mi*16 + lg*4;
        if (sec == 2) {
            // V transposed; 4 consecutive tokens never straddle a batch
            // (cu entries are 512-multiples; span is 4-aligned).
            int b = 0;
            while (cu[b+1] <= r) b++;
            const int q = r - cu[b];
            #pragma unroll
            for (int ni = 0; ni < 4; ni++) {
                const int nl = (n0 - 2*DIM_) + ni*16 + lc;
                const int h = nl >> 6, d = nl & 63;
                u16x4 pk;
                #pragma unroll
                for (int j = 0; j < 4; j++) pk[j] = f2bf(acc[mi][ni][j] + bv[ni]);
                *(u16x4*)&Vt[((size_t)((b*H_ + h)*64 + d))*S_ + q] = pk;
            }
        } else {
            #pragma unroll
            for (int j = 0; j < 4; j++) {
                #pragma unroll
                for (int ni = 0; ni < 4; ni++) {
                    const int nl = (n0 - sec*DIM_) + ni*16 + lc;
                    float v = acc[mi][ni][j] + bv[ni];
                    if (sec == 0) Qu[(size_t)(r+j)*DIM_ + nl] = f2bf(v * QSCALE);
                    else          Ku[(size_t)(r+j)*DIM_ + nl] = f2bf(v);
                }
            }
        }
    }
}

// ---------------------------------------------------------------------------
// K2: flash attention, QBLK=32, 2 waves/block (R14/R18, unchanged).
// ---------------------------------------------------------------------------
__global__ __launch_bounds__(128) void attn_kernel(
    const ushort* __restrict__ Qu, const ushort* __restrict__ Ku,
    const ushort* __restrict__ Vt, const float* __restrict__ bias,
    const float* __restrict__ T, const int* __restrict__ cu,
    float* __restrict__ out)
{
    const int b  = blockIdx.x >> 4, qt = blockIdx.x & 15;   // 16 q-tiles of 32
    const int h  = blockIdx.y;
    const int cu0 = cu[b];
    const int Lb  = cu[b+1] - cu0;
    const int qbase = qt * 32;
    if (qbase >= Lb) return;

    const int t = threadIdx.x, w = t >> 6, l = t & 63, lg = l >> 4, lc = l & 15;

    __shared__ ushort Ks[64][72];     // 9.2 KB
    __shared__ ushort Vs[80][72];     // 11.5 KB  Vs[d][k]; rows 64..79 ones-block
    __shared__ ushort Ps[2][16][72];  // 4.6 KB   per-wave P staging

    // ones-block rows 64..79 (row 64 = 1.0, rest 0)
    for (int i = t; i < 16*9; i += 128) {
        const int row = 64 + i/9, ch = i%9;
        u16x8 v = (u16x8)0;
        if (row == 64 && ch < 8)
            #pragma unroll
            for (int e = 0; e < 8; e++) v[e] = 0x3F80;  // bf16 1.0
        *(u16x8*)&Vs[row][ch*8] = v;
    }

    const float*  bias_b = bias + (size_t)(b*H_ + h)*S_*S_;
    const ushort* kbase  = Ku + (size_t)cu0*DIM_ + h*64;
    const ushort* vbase  = Vt + (size_t)((b*H_ + h)*64)*S_;

    const int krow = t >> 3, kch = t & 7;   // staging: rows krow+i*16, i=0..3

    // C-fragment q rows: rl + j (block-local), j=0..3
    const int rl = w*16 + lg*4;
    int p_[4]; bool val_[4];
    const float* bpr[4];
    #pragma unroll
    for (int j = 0; j < 4; j++) {
        const int r = qbase + rl + j;
        val_[j] = (r < Lb);
        p_[j]   = val_[j] ? r : (Lb - 1);
        bpr[j]  = bias_b + (size_t)p_[j]*S_;
    }

    // Q A-fragments (row = lc), pre-scaled in GEMM epilogue
    int qar = qbase + w*16 + lc; if (qar >= Lb) qar = Lb - 1;
    const ushort* qp = Qu + (size_t)(cu0 + qar)*DIM_ + h*64;
    s16x8 qa0 = *(const s16x8*)(qp + lg*8);
    s16x8 qa1 = *(const s16x8*)(qp + 32 + lg*8);

    f32x4 O[4], lsum;
    #pragma unroll
    for (int d = 0; d < 4; d++) O[d] = (f32x4)0.0f;
    lsum = (f32x4)0.0f;

    // prologue: prefetch tile 0 (bias -> regs, K/V -> regs)
    float pf[4][4];
    u16x8 kr[4], vr[4];
    #pragma unroll
    for (int f = 0; f < 4; f++)
        #pragma unroll
        for (int j = 0; j < 4; j++) pf[f][j] = bpr[j][f*16 + lc];
    #pragma unroll
    for (int i = 0; i < 4; i++) {
        const int r  = krow + i*16;
        const int rc = (r < Lb) ? r : Lb - 1;
        kr[i] = *(const u16x8*)(kbase + (size_t)rc*DIM_ + kch*8);
        vr[i] = *(const u16x8*)(vbase + (size_t)r*S_ + kch*8);
    }

    for (int k0 = 0; k0 < Lb; k0 += 64) {
        __syncthreads();                 // previous tile's LDS reads done
        #pragma unroll
        for (int i = 0; i < 4; i++) {
            const int r = krow + i*16;
            u16x8 kz = (k0 + r < Lb) ? kr[i] : (u16x8)0;
            *(u16x8*)&Ks[r][kch*8] = kz;
            *(u16x8*)&Vs[r][kch*8] = vr[i];
        }
        __syncthreads();

        // consume prefetched bias into score C-frags (pre-mul log2e)
        f32x4 sc[4];
        #pragma unroll
        for (int f = 0; f < 4; f++)
            #pragma unroll
            for (int j = 0; j < 4; j++) sc[f][j] = pf[f][j] * LOG2E;

        // prefetch next tile (in flight during compute below)
        const int kn = k0 + 64;
        if (kn < Lb) {
            #pragma unroll
            for (int f = 0; f < 4; f++)
                #pragma unroll
                for (int j = 0; j < 4; j++) pf[f][j] = bpr[j][kn + f*16 + lc];
            #pragma unroll
            for (int i = 0; i < 4; i++) {
                const int r  = krow + i*16;
                const int rc = (kn + r < Lb) ? kn + r : Lb - 1;
                kr[i] = *(const u16x8*)(kbase + (size_t)rc*DIM_ + kch*8);
                vr[i] = *(const u16x8*)(vbase + (size_t)r*S_ + kn + kch*8);
            }
        }

        // QK^T
        #pragma unroll
        for (int f = 0; f < 4; f++) {
            s16x8 kb0 = *(const s16x8*)&Ks[f*16 + lc][lg*8];
            s16x8 kb1 = *(const s16x8*)&Ks[f*16 + lc][32 + lg*8];
            sc[f] = __builtin_amdgcn_mfma_f32_16x16x32_bf16(qa0, kb0, sc[f], 0,0,0);
            sc[f] = __builtin_amdgcn_mfma_f32_16x16x32_bf16(qa1, kb1, sc[f], 0,0,0);
        }
        // mask last-tile columns beyond Lb (tail kernel owns them)
        if (k0 + 64 > Lb) {
            #pragma unroll
            for (int f = 0; f < 4; f++) {
                const int kcol = k0 + f*16 + lc;
                if (kcol >= Lb)
                    #pragma unroll
                    for (int j = 0; j < 4; j++) sc[f][j] = -1e30f;
            }
        }

        // P = 2^sc directly (no max tracking; bounded scores)
        #pragma unroll
        for (int f = 0; f < 4; f++)
            #pragma unroll
            for (int j = 0; j < 4; j++)
                Ps[w][lg*4 + j][f*16 + lc] = f2bf(exp2f(sc[f][j]));

        s16x8 pa0 = *(const s16x8*)&Ps[w][lc][lg*8];
        s16x8 pa1 = *(const s16x8*)&Ps[w][lc][32 + lg*8];
        #pragma unroll
        for (int df = 0; df < 4; df++) {
            s16x8 vb0 = *(const s16x8*)&Vs[df*16 + lc][lg*8];
            s16x8 vb1 = *(const s16x8*)&Vs[df*16 + lc][32 + lg*8];
            O[df] = __builtin_amdgcn_mfma_f32_16x16x32_bf16(pa0, vb0, O[df], 0,0,0);
            O[df] = __builtin_amdgcn_mfma_f32_16x16x32_bf16(pa1, vb1, O[df], 0,0,0);
        }
        // rowsum via ones-block (col lc==0 of result = sum_k P)
        {
            s16x8 ob0 = *(const s16x8*)&Vs[64 + lc][lg*8];
            s16x8 ob1 = *(const s16x8*)&Vs[64 + lc][32 + lg*8];
            lsum = __builtin_amdgcn_mfma_f32_16x16x32_bf16(pa0, ob0, lsum, 0,0,0);
            lsum = __builtin_amdgcn_mfma_f32_16x16x32_bf16(pa1, ob1, lsum, 0,0,0);
        }
    }

    // denominator: rowsum (valid k) + bias-only tail T; broadcast from lc==0
    #pragma unroll
    for (int j = 0; j < 4; j++) {
        float lj = lsum[j] + T[(size_t)(b*H_ + h)*S_ + p_[j]];
        float inv = 1.0f / lj;
        inv = __shfl(inv, l & 48, 64);       // lane with lc==0 in this group
        if (val_[j]) {
            float* op = out + (size_t)(cu0 + qbase + rl + j)*DIM_ + h*64;
            #pragma unroll
            for (int df = 0; df < 4; df++) op[df*16 + lc] = O[df][j] * inv;
        }
    }
}

// ---------------------------------------------------------------------------
extern "C" void kernel_launch(void* const* d_in, const int* in_sizes, int n_in,
                              void* d_out, int out_size, void* d_ws, size_t ws_size,
                              hipStream_t stream)
{
    const float* hidden  = (const float*)d_in[0];
    const float* W       = (const float*)d_in[1];
    const float* bvec    = (const float*)d_in[2];
    const float* bias    = (const float*)d_in[3];
    const int*   cu      = (const int*)d_in[6];
    float*       out     = (float*)d_out;

    const int NNZ   = in_sizes[0] / DIM_;          // 2048
    const int nrows = NNZ * H_;                    // 24576 tail rows

    char* ws = (char*)d_ws;
    const size_t uB  = (size_t)NNZ * DIM_ * 2;     // one unpadded qkv section
    const size_t vtB = (size_t)B_ * H_ * 64 * S_ * 2;
    ushort* Qu = (ushort*)(ws);
    ushort* Ku = (ushort*)(ws + uB);
    ushort* Vt = (ushort*)(ws + 2*uB);
    float*  T  = (float*)(ws + 2*uB + vtB);

    gemm_tail<<<NGEMM + NTAIL, 256, 0, stream>>>(hidden, W, bvec, bias, cu,
                                                 Qu, Ku, Vt, T, nrows, NNZ);

    dim3 ga(B_*16, H_);                            // (64,12), QBLK=32
    attn_kernel<<<ga, 128, 0, stream>>>(Qu, Ku, Vt, bias, T, cu, out);
}